// Round 1
// baseline (548.467 us; speedup 1.0000x reference)
//
#include <hip/hip_runtime.h>
#include <hip/hip_bf16.h>
#include <math.h>

#define B_SZ 2
#define L_SZ 2048
#define DMODEL 1024
#define DINNER 2048
#define DSTATE 16
#define DTRANK 64
#define M_ROWS (B_SZ * L_SZ)   // 4096

#define CH 32
#define CLEN (L_SZ / CH)
#define CPB 64

#define KSPLIT 8
#define KC (DINNER / KSPLIT)   // 256

typedef short shortx8 __attribute__((ext_vector_type(8)));
typedef float floatx4 __attribute__((ext_vector_type(4)));
typedef float floatx16 __attribute__((ext_vector_type(16)));

__device__ __forceinline__ float softplusf(float x) {
    return fmaxf(x, 0.f) + log1pf(expf(-fabsf(x)));
}
__device__ __forceinline__ float siluf(float x) {
    return x * (1.f / (1.f + expf(-x)));
}

__device__ __forceinline__ void async_ld16(const void* g, void* l) {
    __builtin_amdgcn_global_load_lds(
        (__attribute__((address_space(1))) void*)(unsigned long long)g,
        (__attribute__((address_space(3))) void*)(unsigned int)(unsigned long long)l,
        16, 0, 0);
}

// ---------------------------------------------------------------------------
// R10: in_proj rebuilt as a K-AUGMENTED plain bf16 GEMM (K'=3K=3072):
//   A'' = [x_h | x_l | x_h], B'' = [w_h | w_h | w_l]
//   => sum = xh*wh + xl*wh + xh*wl  (same 3 split-fp32 terms as before).
// Panelized global layout (one 16KB block per 256-row panel x 32-k tile,
// 4 slabs of [256 rows][8 shorts]) so that:
//   - every global_load_lds is a fully-coalesced 1KB wave transaction into
//     a LINEAR LDS dest (m104 constraint respected),
//   - every ds_read_b128 is a 512B-contiguous run -> conflict-free.
// Schedule: 256x256 tile, 4 waves, per-wave 128x128 (4x4 frags of 32x32x16,
// 0.5 LDS-reads/MFMA), 4-buffer LDS ring (128KB), prefetch distance 3,
// counted s_waitcnt vmcnt(16) (NEVER 0 in steady state), raw s_barrier,
// setprio(1) around the MFMA cluster (T3+T4+T5). Race-free by construction:
// tile t+3 overwrites the buffer last read at iteration t-1 (behind barrier).
// ---------------------------------------------------------------------------

// fp32 -> 3-segment panelized bf16.
// LO==1: segs [h, l, h]   (activations / A-side)
// LO==2: segs [h, h, l]   (weights / B-side)
// src is [4096][1024] fp32; dst is panel blocks:
//   short offset = ((p*96 + t)*4 + c)*2048 + rr*8 + j
//   with p=row>>8, rr=row&255, k'=seg*1024+k, t=k'>>5, c=(k'>>3)&3, j=k'&7
template <int LO>
__global__ __launch_bounds__(256) void split3_kernel(
    const float* __restrict__ src, unsigned short* __restrict__ dst)
{
    int i = blockIdx.x * 256 + threadIdx.x;   // 4096 rows x 128 k8-groups
    int row = i & 4095;
    int k8 = i >> 12;
    const float* s = src + (size_t)row * 1024 + k8 * 8;
    float4 v0 = *(const float4*)s;
    float4 v1 = *(const float4*)(s + 4);
    float vs[8] = {v0.x, v0.y, v0.z, v0.w, v1.x, v1.y, v1.z, v1.w};
    unsigned short hs[8], ls[8];
#pragma unroll
    for (int j = 0; j < 8; ++j) {
        __hip_bfloat16 h = __float2bfloat16(vs[j]);
        __hip_bfloat16 l = __float2bfloat16(vs[j] - __bfloat162float(h));
        hs[j] = *(unsigned short*)&h;
        ls[j] = *(unsigned short*)&l;
    }
    shortx8 hv = *(shortx8*)hs;
    shortx8 lv = *(shortx8*)ls;
    int p = row >> 8, rr = row & 255;
    // seg stride in tiles = 32 -> 32*4*2048 = 262144 shorts
    size_t b0 = ((size_t)(p * 96 + (k8 >> 2)) * 4 + (k8 & 3)) * 2048 + rr * 8;
    *(shortx8*)&dst[b0]          = hv;
    *(shortx8*)&dst[b0 + 262144] = (LO == 1) ? lv : hv;
    *(shortx8*)&dst[b0 + 524288] = (LO == 1) ? hv : lv;
}

// Pipelined bf16 GEMM over panelized inputs. KT = K'/32 tiles, NB = n-blocks.
// Grid must be (M/256)*(N/256) blocks, 256 threads.
template <int KT, int NB>
__global__ __launch_bounds__(256, 1) void gemm_pipe_bf16(
    const unsigned short* __restrict__ Ap,
    const unsigned short* __restrict__ Bp,
    float* __restrict__ C, int ldc)
{
    __shared__ unsigned short lds[65536];   // 4 bufs x (A 8192 + B 8192) shorts

    const int tid = threadIdx.x;
    const int w = tid >> 6;
    const int lane = tid & 63;
    const int wm = w >> 1, wn = w & 1;
    const int l31 = lane & 31, lh = lane >> 5;

    // bijective XCD swizzle (gridDim.x % 8 == 0)
    int nwg = gridDim.x;
    int id = blockIdx.x;
    id = (id & 7) * (nwg >> 3) + (id >> 3);
    const int bm = id / NB;
    const int bn = id % NB;

    const unsigned short* ga = Ap + (size_t)bm * KT * 8192;
    const unsigned short* gb = Bp + (size_t)bn * KT * 8192;
    const int soff = w * 512 + lane * 8;     // staged row = w*64 + lane

    // prologue: stage tiles 0..2 into bufs 0..2 (8 loads each)
#pragma unroll
    for (int t = 0; t < 3; ++t) {
        unsigned short* lb = lds + t * 16384;
        const size_t go = (size_t)t * 8192;
#pragma unroll
        for (int c = 0; c < 4; ++c) {
            async_ld16(ga + go + c * 2048 + soff, lb + c * 2048 + w * 512);
            async_ld16(gb + go + c * 2048 + soff, lb + 8192 + c * 2048 + w * 512);
        }
    }
    asm volatile("s_waitcnt vmcnt(16)" ::: "memory");   // tile 0 landed
    __builtin_amdgcn_s_barrier();

    const int arow = (wm * 128 + l31) * 8;
    const int brow = (wn * 128 + l31) * 8;
    floatx16 acc[4][4] = {};

    for (int t = 0; t < KT; ++t) {
        // stage tile t+3 into buf[(t+3)&3] (last read at iteration t-1)
        if (t + 3 < KT) {
            unsigned short* sb = lds + ((t + 3) & 3) * 16384;
            const size_t go = (size_t)(t + 3) * 8192;
#pragma unroll
            for (int c = 0; c < 4; ++c) {
                async_ld16(ga + go + c * 2048 + soff, sb + c * 2048 + w * 512);
                async_ld16(gb + go + c * 2048 + soff, sb + 8192 + c * 2048 + w * 512);
            }
        }
        const unsigned short* lb = lds + (t & 3) * 16384;
        __builtin_amdgcn_s_setprio(1);
#pragma unroll
        for (int ks = 0; ks < 2; ++ks) {
            const int slab = (ks * 2 + lh) * 2048;   // 8-k slab, both halves 2-way-free
            shortx8 a0 = *(const shortx8*)&lb[slab + arow];
            shortx8 a1 = *(const shortx8*)&lb[slab + arow + 256];
            shortx8 a2 = *(const shortx8*)&lb[slab + arow + 512];
            shortx8 a3 = *(const shortx8*)&lb[slab + arow + 768];
            shortx8 b0 = *(const shortx8*)&lb[8192 + slab + brow];
            shortx8 b1 = *(const shortx8*)&lb[8192 + slab + brow + 256];
            shortx8 b2 = *(const shortx8*)&lb[8192 + slab + brow + 512];
            shortx8 b3 = *(const shortx8*)&lb[8192 + slab + brow + 768];
            acc[0][0] = __builtin_amdgcn_mfma_f32_32x32x16_bf16(a0, b0, acc[0][0], 0, 0, 0);
            acc[0][1] = __builtin_amdgcn_mfma_f32_32x32x16_bf16(a0, b1, acc[0][1], 0, 0, 0);
            acc[0][2] = __builtin_amdgcn_mfma_f32_32x32x16_bf16(a0, b2, acc[0][2], 0, 0, 0);
            acc[0][3] = __builtin_amdgcn_mfma_f32_32x32x16_bf16(a0, b3, acc[0][3], 0, 0, 0);
            acc[1][0] = __builtin_amdgcn_mfma_f32_32x32x16_bf16(a1, b0, acc[1][0], 0, 0, 0);
            acc[1][1] = __builtin_amdgcn_mfma_f32_32x32x16_bf16(a1, b1, acc[1][1], 0, 0, 0);
            acc[1][2] = __builtin_amdgcn_mfma_f32_32x32x16_bf16(a1, b2, acc[1][2], 0, 0, 0);
            acc[1][3] = __builtin_amdgcn_mfma_f32_32x32x16_bf16(a1, b3, acc[1][3], 0, 0, 0);
            acc[2][0] = __builtin_amdgcn_mfma_f32_32x32x16_bf16(a2, b0, acc[2][0], 0, 0, 0);
            acc[2][1] = __builtin_amdgcn_mfma_f32_32x32x16_bf16(a2, b1, acc[2][1], 0, 0, 0);
            acc[2][2] = __builtin_amdgcn_mfma_f32_32x32x16_bf16(a2, b2, acc[2][2], 0, 0, 0);
            acc[2][3] = __builtin_amdgcn_mfma_f32_32x32x16_bf16(a2, b3, acc[2][3], 0, 0, 0);
            acc[3][0] = __builtin_amdgcn_mfma_f32_32x32x16_bf16(a3, b0, acc[3][0], 0, 0, 0);
            acc[3][1] = __builtin_amdgcn_mfma_f32_32x32x16_bf16(a3, b1, acc[3][1], 0, 0, 0);
            acc[3][2] = __builtin_amdgcn_mfma_f32_32x32x16_bf16(a3, b2, acc[3][2], 0, 0, 0);
            acc[3][3] = __builtin_amdgcn_mfma_f32_32x32x16_bf16(a3, b3, acc[3][3], 0, 0, 0);
        }
        __builtin_amdgcn_s_setprio(0);
        // drain exactly tile t+1 before next iteration reads it (counted, not 0)
        if (t < KT - 3)       { asm volatile("s_waitcnt vmcnt(16)" ::: "memory"); }
        else if (t == KT - 3) { asm volatile("s_waitcnt vmcnt(8)"  ::: "memory"); }
        else if (t == KT - 2) { asm volatile("s_waitcnt vmcnt(0)"  ::: "memory"); }
        __builtin_amdgcn_s_barrier();
    }

    // epilogue: C/D layout col=lane&31, row=(reg&3)+8*(reg>>2)+4*(lane>>5) (m74/m101)
#pragma unroll
    for (int i = 0; i < 4; ++i) {
#pragma unroll
        for (int j = 0; j < 4; ++j) {
            int col = bn * 256 + wn * 128 + j * 32 + l31;
#pragma unroll
            for (int r = 0; r < 16; ++r) {
                int row = bm * 256 + wm * 128 + i * 32 + (r & 3) + 8 * (r >> 2) + 4 * lh;
                C[(size_t)row * ldc + col] = acc[i][j][r];
            }
        }
    }
}

// ---------------------------------------------------------------------------
// bf16 MFMA GEMM (R8 structure) -- still used for out_proj this round (control).
// ---------------------------------------------------------------------------
template <int BN, int KP>
__global__ __launch_bounds__(256) void gemm_bf16_nt(
    const unsigned short* __restrict__ A,
    const unsigned short* __restrict__ Bm,
    float* __restrict__ C, int ldc)
{
    constexpr int TN32 = BN / 64;                 // 32-wide n-tiles per wave
    __shared__ unsigned short As[2 * 8192];       // [seg][t][128 rows][32 k]
    __shared__ unsigned short Bs[2 * BN * 64];    // [seg][t][BN rows][32 k]

    const int tid = threadIdx.x;
    const int w = tid >> 6;
    const int lane = tid & 63;
    const int wm = w >> 1, wn = w & 1;
    const int m0 = blockIdx.y * 128;
    const int n0 = blockIdx.x * BN;

    const int r4 = lane >> 2;                        // staging row in 16-group
    const int csw = (lane & 3) ^ ((r4 >> 1) & 3);    // swizzled source chunk
    const int gk = csw * 8;                          // shorts offset
    const int l31 = lane & 31;
    const int khalf = lane >> 5;                     // 0/1: k-half within 16
    const int rsw = (l31 >> 1) & 3;                  // read-side swizzle key

    floatx16 acc[2][TN32] = {};

    for (int k0 = 0; k0 < KP; k0 += 64) {
#pragma unroll
        for (int seg = 0; seg < 2; ++seg) {
            const unsigned short* Asrc = A + seg * KP;
            const unsigned short* Bsrc = Bm + seg * KP;
#pragma unroll
            for (int t = 0; t < 2; ++t) {
#pragma unroll
                for (int jj = 0; jj < 2; ++jj) {
                    int j = w + jj * 4;
                    async_ld16(Asrc + (size_t)(m0 + j * 16 + r4) * (2 * KP) + k0 + t * 32 + gk,
                               &As[seg * 8192 + t * 4096 + j * 512]);
                }
#pragma unroll
                for (int jj = 0; jj < BN / 64; ++jj) {
                    int j = w + jj * 4;
                    async_ld16(Bsrc + (size_t)(n0 + j * 16 + r4) * (2 * KP) + k0 + t * 32 + gk,
                               &Bs[seg * BN * 64 + t * BN * 32 + j * 512]);
                }
            }
        }
        __syncthreads();

#pragma unroll
        for (int t = 0; t < 2; ++t) {
#pragma unroll
            for (int kk = 0; kk < 2; ++kk) {
                const int pos = ((kk * 2 + khalf) ^ rsw) << 3;
                shortx8 ah[2], al[2], bh[TN32], bl[TN32];
#pragma unroll
                for (int i = 0; i < 2; ++i) {
                    int row = wm * 64 + i * 32 + l31;
                    ah[i] = *(const shortx8*)&As[t * 4096 + row * 32 + pos];
                    al[i] = *(const shortx8*)&As[8192 + t * 4096 + row * 32 + pos];
                }
#pragma unroll
                for (int j = 0; j < TN32; ++j) {
                    int col = wn * (BN / 2) + j * 32 + l31;
                    bh[j] = *(const shortx8*)&Bs[t * BN * 32 + col * 32 + pos];
                    bl[j] = *(const shortx8*)&Bs[BN * 64 + t * BN * 32 + col * 32 + pos];
                }
#pragma unroll
                for (int i = 0; i < 2; ++i)
#pragma unroll
                    for (int j = 0; j < TN32; ++j) {
                        acc[i][j] = __builtin_amdgcn_mfma_f32_32x32x16_bf16(ah[i], bh[j], acc[i][j], 0, 0, 0);
                        acc[i][j] = __builtin_amdgcn_mfma_f32_32x32x16_bf16(ah[i], bl[j], acc[i][j], 0, 0, 0);
                        acc[i][j] = __builtin_amdgcn_mfma_f32_32x32x16_bf16(al[i], bh[j], acc[i][j], 0, 0, 0);
                    }
            }
        }
        __syncthreads();
    }

#pragma unroll
    for (int i = 0; i < 2; ++i) {
#pragma unroll
        for (int j = 0; j < TN32; ++j) {
            int col = n0 + wn * (BN / 2) + j * 32 + l31;
#pragma unroll
            for (int r = 0; r < 16; ++r) {
                int row = m0 + wm * 64 + i * 32 + (r & 3) + 8 * (r >> 2) + 4 * khalf;
                C[(size_t)row * ldc + col] = acc[i][j][r];
            }
        }
    }
}

// ---------------------------------------------------------------------------
// fp32 -> 2-segment split-bf16: row = [hi (K) | lo (K)], stride 2K (out_proj path)
// ---------------------------------------------------------------------------
__global__ __launch_bounds__(256) void split2_kernel(
    const float* __restrict__ src, unsigned short* __restrict__ dst, int K)
{
    int i = blockIdx.x * 256 + threadIdx.x;
    int m = i / K;
    int k = i - m * K;
    float a = src[i];
    __hip_bfloat16 h = __float2bfloat16(a);
    __hip_bfloat16 l = __float2bfloat16(a - __bfloat162float(h));
    unsigned short* row = dst + (size_t)m * 2 * K;
    row[k] = *(unsigned short*)&h;
    row[K + k] = *(unsigned short*)&l;
}

// ---------------------------------------------------------------------------
// x_proj split-K partial GEMM + reduce
// ---------------------------------------------------------------------------
__global__ __launch_bounds__(256) void xproj_splitk(
    const float* __restrict__ u, const float* __restrict__ Wx,
    float* __restrict__ Cp)
{
    __shared__ float As[16][68];
    __shared__ float Bs[16][100];

    const int tid = threadIdx.x;
    const int ks = blockIdx.x;
    const int m0 = blockIdx.y * 64;
    const int tx = tid & 15;
    const int ty = tid >> 4;

    float acc[4][6] = {};

    const int arow = tid >> 2;
    const int akk = (tid & 3) * 4;

    for (int k0 = ks * KC; k0 < (ks + 1) * KC; k0 += 16) {
        {
            float4 v = *(const float4*)&u[(size_t)(m0 + arow) * DINNER + k0 + akk];
            As[akk + 0][arow] = v.x;
            As[akk + 1][arow] = v.y;
            As[akk + 2][arow] = v.z;
            As[akk + 3][arow] = v.w;
        }
        for (int idx = tid; idx < 384; idx += 256) {
            int row = idx >> 2;
            int kk = (idx & 3) * 4;
            float4 v = *(const float4*)&Wx[(size_t)row * DINNER + k0 + kk];
            Bs[kk + 0][row] = v.x;
            Bs[kk + 1][row] = v.y;
            Bs[kk + 2][row] = v.z;
            Bs[kk + 3][row] = v.w;
        }
        __syncthreads();

#pragma unroll
        for (int k = 0; k < 16; ++k) {
            float a[4], b[6];
#pragma unroll
            for (int i = 0; i < 4; ++i) a[i] = As[k][ty * 4 + i];
#pragma unroll
            for (int j = 0; j < 6; ++j) b[j] = Bs[k][tx * 6 + j];
#pragma unroll
            for (int i = 0; i < 4; ++i)
#pragma unroll
                for (int j = 0; j < 6; ++j) acc[i][j] = fmaf(a[i], b[j], acc[i][j]);
        }
        __syncthreads();
    }

    float* outp = Cp + ((size_t)ks * M_ROWS + m0) * 96;
#pragma unroll
    for (int i = 0; i < 4; ++i)
#pragma unroll
        for (int j = 0; j < 6; ++j)
            outp[(ty * 4 + i) * 96 + tx * 6 + j] = acc[i][j];
}

__global__ __launch_bounds__(256) void xproj_reduce(
    const float* __restrict__ Cp, float* __restrict__ xdbl)
{
    int i = blockIdx.x * 256 + threadIdx.x;
    float s = 0.f;
#pragma unroll
    for (int c = 0; c < KSPLIT; ++c)
        s += Cp[(size_t)c * M_ROWS * 96 + i];
    xdbl[i] = s;
}

// ---------------------------------------------------------------------------
// fp32 GEMM (dt_proj, K=64)
// ---------------------------------------------------------------------------
template <int BM, int BN, int BK, int TM, int TN, bool BOUND_N, int EPI>
__global__ __launch_bounds__(256) void gemm_nt(
    const float* __restrict__ A, int lda,
    const float* __restrict__ Bmat, int ldb,
    float* __restrict__ C, int ldc,
    int M, int N, int K, const float* __restrict__ bias)
{
    __shared__ float As[BK][BM + 4];
    __shared__ float Bs[BK][BN + 4];

    const int tid = threadIdx.x;
    const int tx = tid % (BN / TN);
    const int ty = tid / (BN / TN);
    const int m0 = blockIdx.y * BM;
    const int n0 = blockIdx.x * BN;

    float acc[TM][TN];
#pragma unroll
    for (int i = 0; i < TM; ++i)
#pragma unroll
        for (int j = 0; j < TN; ++j) acc[i][j] = 0.f;

    for (int k0 = 0; k0 < K; k0 += BK) {
        for (int idx = tid * 4; idx < BM * BK; idx += 256 * 4) {
            int row = idx / BK;
            int kk = idx % BK;
            float4 v = *(const float4*)&A[(size_t)(m0 + row) * lda + k0 + kk];
            As[kk + 0][row] = v.x;
            As[kk + 1][row] = v.y;
            As[kk + 2][row] = v.z;
            As[kk + 3][row] = v.w;
        }
        for (int idx = tid * 4; idx < BN * BK; idx += 256 * 4) {
            int row = idx / BK;
            int kk = idx % BK;
            float4 v;
            if (!BOUND_N || (n0 + row) < N)
                v = *(const float4*)&Bmat[(size_t)(n0 + row) * ldb + k0 + kk];
            else
                v = make_float4(0.f, 0.f, 0.f, 0.f);
            Bs[kk + 0][row] = v.x;
            Bs[kk + 1][row] = v.y;
            Bs[kk + 2][row] = v.z;
            Bs[kk + 3][row] = v.w;
        }
        __syncthreads();

#pragma unroll
        for (int k = 0; k < BK; ++k) {
            float a[TM], b[TN];
#pragma unroll
            for (int i = 0; i < TM; ++i) a[i] = As[k][ty * TM + i];
#pragma unroll
            for (int j = 0; j < TN; ++j) b[j] = Bs[k][tx * TN + j];
#pragma unroll
            for (int i = 0; i < TM; ++i)
#pragma unroll
                for (int j = 0; j < TN; ++j) acc[i][j] = fmaf(a[i], b[j], acc[i][j]);
        }
        __syncthreads();
    }

#pragma unroll
    for (int i = 0; i < TM; ++i) {
        int m = m0 + ty * TM + i;
#pragma unroll
        for (int j = 0; j < TN; ++j) {
            int n = n0 + tx * TN + j;
            if (BOUND_N && n >= N) continue;
            float v = acc[i][j];
            if (EPI == 1) v = softplusf(v + bias[n]);
            C[(size_t)m * ldc + n] = v;
        }
    }
}

// ---------------------------------------------------------------------------
// conv + silu, float4 over channels
// ---------------------------------------------------------------------------
__global__ __launch_bounds__(256) void conv_silu_v4(
    const float* __restrict__ xz, const float* __restrict__ cw,
    const float* __restrict__ cb, float* __restrict__ u)
{
    int i = blockIdx.x * 256 + threadIdx.x;      // over M_ROWS * 512
    int dq = (i & 511) << 2;
    int bl = i >> 9;
    int b = bl >> 11;
    int l = bl & 2047;

    float4 W0 = *(const float4*)&cw[(dq + 0) * 4];
    float4 W1 = *(const float4*)&cw[(dq + 1) * 4];
    float4 W2 = *(const float4*)&cw[(dq + 2) * 4];
    float4 W3 = *(const float4*)&cw[(dq + 3) * 4];
    float4 acc = *(const float4*)&cb[dq];

#pragma unroll
    for (int k = 0; k < 4; ++k) {
        int ls = l + k - 3;
        if (ls >= 0) {
            float4 v = *(const float4*)&xz[((size_t)(b << 11) + ls) * 4096 + dq];
            acc.x = fmaf(v.x, ((const float*)&W0)[k], acc.x);
            acc.y = fmaf(v.y, ((const float*)&W1)[k], acc.y);
            acc.z = fmaf(v.z, ((const float*)&W2)[k], acc.z);
            acc.w = fmaf(v.w, ((const float*)&W3)[k], acc.w);
        }
    }
    float4 r = make_float4(siluf(acc.x), siluf(acc.y), siluf(acc.z), siluf(acc.w));
    *(float4*)&u[(size_t)bl * DINNER + dq] = r;
}

// ---------------------------------------------------------------------------
// Chunked selective scan (3 passes). PASS3 fuses gate + split-bf16 y2.
// ---------------------------------------------------------------------------
template <bool PASS3>
__global__ __launch_bounds__(256) void scan_chunk(
    const float* __restrict__ dbuf, const float* __restrict__ ubuf,
    const float* __restrict__ xdbl, const float* __restrict__ A_log,
    const float* __restrict__ Dv,
    float* __restrict__ Pbuf, float* __restrict__ Sbuf,
    const float* __restrict__ xz, unsigned short* __restrict__ y2)
{
    __shared__ float sd[16][CPB];
    __shared__ float su[16][CPB];
    __shared__ float sB[16][DSTATE];
    __shared__ float sC[16][DSTATE];

    const int tid = threadIdx.x;
    const int c    = blockIdx.x % CH;
    const int dblk = (blockIdx.x / CH) % (DINNER / CPB);
    const int b    = blockIdx.x / (CH * (DINNER / CPB));
    const int d0 = dblk * CPB;
    const int dg = tid >> 2;
    const int q  = tid & 3;
    const int d  = d0 + dg;
    const size_t base_bl = (size_t)b * L_SZ + (size_t)c * CLEN;

    float Ac[4], h[4];
    float sdl = 0.f;
#pragma unroll
    for (int j = 0; j < 4; ++j)
        Ac[j] = -expf(A_log[d * DSTATE + 4 * q + j]);
    const size_t psoff = (((size_t)b * CH + c) * DINNER + d0) * DSTATE + (size_t)tid * 4;
    if (PASS3) {
        float4 h0 = *(const float4*)&Sbuf[psoff];
        h[0] = h0.x; h[1] = h0.y; h[2] = h0.z; h[3] = h0.w;
    } else {
        h[0] = h[1] = h[2] = h[3] = 0.f;
    }
    const float Dd = PASS3 ? Dv[d] : 0.f;

    const int ls = tid >> 4;
    const int g4 = (tid & 15) * 4;
    const int ln = tid & 15;

    float4 r_d = *(const float4*)&dbuf[(base_bl + ls) * DINNER + d0 + g4];
    float4 r_u = *(const float4*)&ubuf[(base_bl + ls) * DINNER + d0 + g4];
    float r_B = xdbl[(base_bl + ls) * 96 + 64 + ln];
    float r_C = xdbl[(base_bl + ls) * 96 + 80 + ln];

    for (int l0 = 0; l0 < CLEN; l0 += 16) {
        __syncthreads();
        *(float4*)&sd[ls][g4] = r_d;
        *(float4*)&su[ls][g4] = r_u;
        sB[ls][ln] = r_B;
        sC[ls][ln] = r_C;
        __syncthreads();

        if (l0 + 16 < CLEN) {
            r_d = *(const float4*)&dbuf[(base_bl + l0 + 16 + ls) * DINNER + d0 + g4];
            r_u = *(const float4*)&ubuf[(base_bl + l0 + 16 + ls) * DINNER + d0 + g4];
            r_B = xdbl[(base_bl + l0 + 16 + ls) * 96 + 64 + ln];
            r_C = xdbl[(base_bl + l0 + 16 + ls) * 96 + 80 + ln];
        }

#pragma unroll
        for (int s = 0; s < 16; ++s) {
            float dl = sd[s][dg];
            float ul = su[s][dg];
            float4 Bv = *(float4*)&sB[s][4 * q];
            float dbu = dl * ul;
            float dA0 = expf(dl * Ac[0]);
            float dA1 = expf(dl * Ac[1]);
            float dA2 = expf(dl * Ac[2]);
            float dA3 = expf(dl * Ac[3]);
            h[0] = fmaf(dA0, h[0], dbu * Bv.x);
            h[1] = fmaf(dA1, h[1], dbu * Bv.y);
            h[2] = fmaf(dA2, h[2], dbu * Bv.z);
            h[3] = fmaf(dA3, h[3], dbu * Bv.w);
            if (!PASS3) {
                sdl += dl;
            } else {
                float4 Cv = *(float4*)&sC[s][4 * q];
                float y = h[0] * Cv.x + h[1] * Cv.y + h[2] * Cv.z + h[3] * Cv.w;
                y += __shfl_xor(y, 1);
                y += __shfl_xor(y, 2);
                if (q == 0) su[s][dg] = fmaf(ul, Dd, y);
            }
        }

        if (PASS3) {
            __syncthreads();
            size_t row = base_bl + l0 + ls;
            float4 yv = *(float4*)&su[ls][g4];
            float4 rv = *(const float4*)&xz[row * 4096 + 2048 + d0 + g4];
            float a0 = yv.x * siluf(rv.x);
            float a1 = yv.y * siluf(rv.y);
            float a2 = yv.z * siluf(rv.z);
            float a3 = yv.w * siluf(rv.w);
            __hip_bfloat16 h0 = __float2bfloat16(a0), h1 = __float2bfloat16(a1);
            __hip_bfloat16 h2 = __float2bfloat16(a2), h3 = __float2bfloat16(a3);
            __hip_bfloat16 l0b = __float2bfloat16(a0 - __bfloat162float(h0));
            __hip_bfloat16 l1b = __float2bfloat16(a1 - __bfloat162float(h1));
            __hip_bfloat16 l2b = __float2bfloat16(a2 - __bfloat162float(h2));
            __hip_bfloat16 l3b = __float2bfloat16(a3 - __bfloat162float(h3));
            ushort4 hv = make_ushort4(*(unsigned short*)&h0, *(unsigned short*)&h1,
                                      *(unsigned short*)&h2, *(unsigned short*)&h3);
            ushort4 lv = make_ushort4(*(unsigned short*)&l0b, *(unsigned short*)&l1b,
                                      *(unsigned short*)&l2b, *(unsigned short*)&l3b);
            unsigned short* yrow = y2 + row * 2 * DINNER + d0 + g4;
            *(ushort4*)&yrow[0] = hv;
            *(ushort4*)&yrow[DINNER] = lv;
        }
    }

    if (!PASS3) {
        *(float4*)&Pbuf[psoff] = make_float4(expf(Ac[0] * sdl), expf(Ac[1] * sdl),
                                             expf(Ac[2] * sdl), expf(Ac[3] * sdl));
        *(float4*)&Sbuf[psoff] = make_float4(h[0], h[1], h[2], h[3]);
    }
}

__global__ __launch_bounds__(256) void scan_combine(
    const float* __restrict__ Pbuf, float* __restrict__ Sbuf)
{
    int t = blockIdx.x * 256 + threadIdx.x;
    int b = t >> 15;
    int rem = t & 32767;
    size_t base = (size_t)b * CH * DINNER * DSTATE + rem;
    float H = 0.f;
#pragma unroll 4
    for (int c = 0; c < CH; ++c) {
        size_t off = base + (size_t)c * DINNER * DSTATE;
        float S = Sbuf[off];
        float P = Pbuf[off];
        Sbuf[off] = H;
        H = fmaf(P, H, S);
    }
}

// ---------------------------------------------------------------------------
extern "C" void kernel_launch(void* const* d_in, const int* in_sizes, int n_in,
                              void* d_out, int out_size, void* d_ws, size_t ws_size,
                              hipStream_t stream)
{
    const float* x          = (const float*)d_in[0];
    const float* in_proj_w  = (const float*)d_in[1];
    const float* conv_w     = (const float*)d_in[2];
    const float* conv_b     = (const float*)d_in[3];
    const float* x_proj_w   = (const float*)d_in[4];
    const float* dt_proj_w  = (const float*)d_in[5];
    const float* dt_proj_b  = (const float*)d_in[6];
    const float* A_log      = (const float*)d_in[7];
    const float* Dv         = (const float*)d_in[8];
    const float* out_proj_w = (const float*)d_in[9];
    float* out = (float*)d_out;

    // workspace layout (bytes):
    char* w = (char*)d_ws;
    float* xz   = (float*)(w);                       // 64 MB
    float* u    = (float*)(w + 67108864);            // 32 MB (written step 3)
    float* dbuf = (float*)(w + 100663296);           // 32 MB (written step 5)
    float* xdbl = (float*)(w + 134217728);           // 1.5 MB
    float* Pbuf = (float*)(w + 135790592);           // 8 MB
    float* Sbuf = (float*)(w + 144179200);           // 8 MB (ends 152567808)
    unsigned short* y2  = (unsigned short*)(w + 152567808);   // 32 MB [4096][4096] (stage 6+)
    unsigned short* w2b = (unsigned short*)(w + 135790592);   // 8 MB over Pbuf (dead at 7)
    float* Cp = (float*)(w + 152567808);             // xproj partials (dead at 4, pre-y2)
    // panelized 3-seg bf16 inputs for in_proj; ALIAS u / dbuf (dead after step 2)
    unsigned short* x2p  = (unsigned short*)(w + 67108864);   // 24 MB over u
    unsigned short* w2ap = (unsigned short*)(w + 100663296);  // 24 MB over dbuf

    // 1) split x / in_proj_w to 3-segment panelized bf16 (K' = 3072)
    split3_kernel<1><<<2048, 256, 0, stream>>>(x, x2p);          // [h,l,h]
    split3_kernel<2><<<2048, 256, 0, stream>>>(in_proj_w, w2ap); // [h,h,l]
    // 2) in_proj via pipelined 32x32x16 MFMA GEMM (KT=96 tiles, 16 n-blocks)
    gemm_pipe_bf16<96, 16><<<256, 256, 0, stream>>>(x2p, w2ap, xz, 4096);
    // 3) conv + silu -> u (overwrites x2p, dead)
    conv_silu_v4<<<(M_ROWS * 512) / 256, 256, 0, stream>>>(xz, conv_w, conv_b, u);
    // 4) x_proj via split-K
    {
        dim3 g(KSPLIT, M_ROWS / 64);
        xproj_splitk<<<g, 256, 0, stream>>>(u, x_proj_w, Cp);
        xproj_reduce<<<(M_ROWS * 96) / 256, 256, 0, stream>>>(Cp, xdbl);
    }
    // 5) dt_proj + softplus -> dbuf (fp32, K=64; overwrites w2ap, dead)
    {
        dim3 g(2048 / 128, M_ROWS / 128);
        gemm_nt<128, 128, 16, 8, 8, false, 1><<<g, 256, 0, stream>>>(
            xdbl, 96, dt_proj_w, 64, dbuf, 2048, M_ROWS, 2048, 64, dt_proj_b);
    }
    // 6) chunked selective scan; pass3 fuses gate + split into y2
    {
        const int nblk = B_SZ * (DINNER / CPB) * CH;
        scan_chunk<false><<<nblk, 256, 0, stream>>>(dbuf, u, xdbl, A_log, Dv, Pbuf, Sbuf, nullptr, nullptr);
        scan_combine<<<B_SZ * DINNER * DSTATE / 256, 256, 0, stream>>>(Pbuf, Sbuf);
        scan_chunk<true><<<nblk, 256, 0, stream>>>(dbuf, u, xdbl, A_log, Dv, nullptr, Sbuf, xz, y2);
    }
    // 7) split out_proj_w (2-seg, old path)
    split2_kernel<<<(DMODEL * DINNER) / 256, 256, 0, stream>>>(out_proj_w, w2b, DINNER);
    // 8) out_proj via 32x32x16 MFMA (R8 structure, control)
    {
        dim3 g(1024 / 64, M_ROWS / 128);
        gemm_bf16_nt<64, 2048><<<g, 256, 0, stream>>>(y2, w2b, out, 1024);
    }
}